// Round 1
// baseline (204.515 us; speedup 1.0000x reference)
//
#include <hip/hip_runtime.h>

// SpecularityMask: x shape (64, 512, 512, 2) f32, interleaved (s, v) pairs.
// out[i] = (v*255 / (1 + s*255) > 2.0f) ? 0.0f : 1.0f
//
// Memory-bound streaming kernel. Each lane loads one float4 = (s0,v0,s1,v1)
// (16 B, perfectly coalesced) and stores one float2 (8 B).
//
// fp contract(off): must match the reference's plain f32 mul/add/div/cmp
// sequence bit-exactly — an fma on (1 + s*255) can flip the comparison for
// samples within 1 ulp of the threshold boundary, and with 16.7M samples
// ~2 such samples are expected.

__global__ void __launch_bounds__(256)
spec_mask_kernel(const float4* __restrict__ in, float2* __restrict__ out, int n2) {
#pragma clang fp contract(off)
    int idx = blockIdx.x * blockDim.x + threadIdx.x;
    int stride = gridDim.x * blockDim.x;
    for (int i = idx; i < n2; i += stride) {
        float4 p = in[i];                 // (s0, v0, s1, v1)
        float d0 = 1.0f + p.x * 255.0f;   // plain add+mul, no fma
        float n0 = p.y * 255.0f;
        float r0 = n0 / d0;               // IEEE f32 divide (no rcp approx)
        float d1 = 1.0f + p.z * 255.0f;
        float n1 = p.w * 255.0f;
        float r1 = n1 / d1;
        float2 o;
        o.x = (r0 > 2.0f) ? 0.0f : 1.0f;
        o.y = (r1 > 2.0f) ? 0.0f : 1.0f;
        out[i] = o;
    }
}

extern "C" void kernel_launch(void* const* d_in, const int* in_sizes, int n_in,
                              void* d_out, int out_size, void* d_ws, size_t ws_size,
                              hipStream_t stream) {
    const float4* in = (const float4*)d_in[0];
    float2* out = (float2*)d_out;
    int n2 = out_size / 2;                // 8,388,608 float4 work items
    int block = 256;
    int grid = (n2 + block - 1) / block;
    if (grid > 2048) grid = 2048;         // grid-stride beyond this
    spec_mask_kernel<<<grid, block, 0, stream>>>(in, out, n2);
}